// Round 2
// baseline (413.231 us; speedup 1.0000x reference)
//
#include <hip/hip_runtime.h>
#include <math.h>

// ---------------------------------------------------------------------------
// EG-GAT layer v2 — hoist softmax stats out of the per-edge hot loop:
//   K1 h-proj:  h[N,128] = x @ W_node
//   K2 edge:    logits[E,8] (colsum-factored edge term) + degree histogram
//   K3 alloc:   CSR segment starts (wave-aggregated cursor, no scan)
//   K4 scatter: csr[pos] = (eid, src)  packed int2
//   K5 stats:   m[n,h], 1/denom[n,h]  (two cheap CSR passes, 400k threads)
//   K6 agg:     out[n,h,d] = invden * sum_j exp2(lg-m) * sigmoid(ev) * k
//               -- no shuffles, no online rescale, 1-FMA loop carry
// ---------------------------------------------------------------------------

#define LOG2E 1.44269504088896340736f

__global__ __launch_bounds__(256) void k_hproj(
    const float* __restrict__ x, const float* __restrict__ Wn,
    float* __restrict__ h, int N)
{
    int t  = threadIdx.x;
    int cg = t & 31, rg = t >> 5;
    int c0 = cg * 4;
    int hh = c0 >> 4, d0 = c0 & 15;
    int r0 = blockIdx.x * 64 + rg * 8;
    const float* wbase = Wn + hh * 2048 + d0;

    float acc[8][4];
#pragma unroll
    for (int j = 0; j < 8; ++j)
#pragma unroll
        for (int q = 0; q < 4; ++q) acc[j][q] = 0.f;

    int rr[8];
#pragma unroll
    for (int j = 0; j < 8; ++j) { int n = r0 + j; rr[j] = (n < N) ? n : (N - 1); }

    for (int k0 = 0; k0 < 128; k0 += 4) {
        float4 b0 = *(const float4*)(wbase + (k0 + 0) * 16);
        float4 b1 = *(const float4*)(wbase + (k0 + 1) * 16);
        float4 b2 = *(const float4*)(wbase + (k0 + 2) * 16);
        float4 b3 = *(const float4*)(wbase + (k0 + 3) * 16);
#pragma unroll
        for (int j = 0; j < 8; ++j) {
            float4 a = *(const float4*)(x + (size_t)rr[j] * 128 + k0);
            acc[j][0] += a.x * b0.x + a.y * b1.x + a.z * b2.x + a.w * b3.x;
            acc[j][1] += a.x * b0.y + a.y * b1.y + a.z * b2.y + a.w * b3.y;
            acc[j][2] += a.x * b0.z + a.y * b1.z + a.z * b2.z + a.w * b3.z;
            acc[j][3] += a.x * b0.w + a.y * b1.w + a.z * b2.w + a.w * b3.w;
        }
    }
#pragma unroll
    for (int j = 0; j < 8; ++j) {
        int n = r0 + j;
        if (n < N) {
            float4 v = make_float4(acc[j][0], acc[j][1], acc[j][2], acc[j][3]);
            *(float4*)(h + (size_t)n * 128 + c0) = v;
        }
    }
}

// K2: thread per (edge, head). logits_scaled = leaky_relu((q.k + ea.cs)*0.25)*log2e
// Also does the degree histogram (lane h==0).
__global__ __launch_bounds__(256) void k_edge(
    const float* __restrict__ h, const float* __restrict__ ea,
    const float* __restrict__ We, const int* __restrict__ src,
    const int* __restrict__ dst, float* __restrict__ logits,
    int* __restrict__ counts, int E)
{
    __shared__ float cs[128];                 // cs[h*16+i] = sum_d We[h][i][d]
    int t = threadIdx.x;
    if (t < 128) {
        const float4* wr = (const float4*)(We + t * 16);
        float4 w0 = wr[0], w1 = wr[1], w2 = wr[2], w3 = wr[3];
        cs[t] = (w0.x + w0.y + w0.z + w0.w) + (w1.x + w1.y + w1.z + w1.w)
              + (w2.x + w2.y + w2.z + w2.w) + (w3.x + w3.y + w3.z + w3.w);
    }
    __syncthreads();

    int gid = blockIdx.x * 256 + t;
    int e = gid >> 3;
    if (e >= E) return;
    int hh = gid & 7;
    int dn = dst[e], sn = src[e];

    const float4* qp = (const float4*)(h + (size_t)dn * 128 + hh * 16);
    const float4* kp = (const float4*)(h + (size_t)sn * 128 + hh * 16);
    float4 q0 = qp[0], q1 = qp[1], q2 = qp[2], q3 = qp[3];
    float4 k0 = kp[0], k1 = kp[1], k2 = kp[2], k3 = kp[3];
    float qk = q0.x*k0.x + q0.y*k0.y + q0.z*k0.z + q0.w*k0.w
             + q1.x*k1.x + q1.y*k1.y + q1.z*k1.z + q1.w*k1.w
             + q2.x*k2.x + q2.y*k2.y + q2.z*k2.z + q2.w*k2.w
             + q3.x*k3.x + q3.y*k3.y + q3.z*k3.z + q3.w*k3.w;

    const float4* ap = (const float4*)(ea + (size_t)e * 16);
    float4 a0 = ap[0], a1 = ap[1], a2 = ap[2], a3 = ap[3];
    const float4* cp = (const float4*)(cs + hh * 16);
    float4 c0 = cp[0], c1 = cp[1], c2 = cp[2], c3 = cp[3];
    float es = a0.x*c0.x + a0.y*c0.y + a0.z*c0.z + a0.w*c0.w
             + a1.x*c1.x + a1.y*c1.y + a1.z*c1.z + a1.w*c1.w
             + a2.x*c2.x + a2.y*c2.y + a2.z*c2.z + a2.w*c2.w
             + a3.x*c3.x + a3.y*c3.y + a3.z*c3.z + a3.w*c3.w;

    float lg = (qk + es) * 0.25f;
    lg = (lg > 0.f) ? lg : 0.2f * lg;         // leaky_relu
    logits[(size_t)e * 8 + hh] = lg * LOG2E;  // pre-scale for exp2

    if (hh == 0) atomicAdd(counts + dn, 1);
}

__global__ __launch_bounds__(256) void k_alloc(
    const int* __restrict__ counts, int* __restrict__ start,
    int* __restrict__ cursor, int* __restrict__ gcur, int N)
{
    int i = blockIdx.x * 256 + threadIdx.x;
    int lane = threadIdx.x & 63;
    int v = (i < N) ? counts[i] : 0;
    int incl = v;
#pragma unroll
    for (int o = 1; o < 64; o <<= 1) {
        int u = __shfl_up(incl, o);
        if (lane >= o) incl += u;
    }
    int total = __shfl(incl, 63);
    int base = 0;
    if (lane == 63) base = atomicAdd(gcur, total);
    base = __shfl(base, 63);
    int st = base + incl - v;
    if (i < N) { start[i] = st; cursor[i] = st; }
}

__global__ __launch_bounds__(256) void k_scatter(
    const int* __restrict__ src, const int* __restrict__ dst,
    int* __restrict__ cursor, int2* __restrict__ csr, int E)
{
    int e = blockIdx.x * 256 + threadIdx.x;
    if (e < E) {
        int dn = dst[e];
        int pos = atomicAdd(cursor + dn, 1);
        csr[pos] = make_int2(e, src[e]);
    }
}

// K5: thread per (node, head): segment max then exp2-sum (logits L2-hot).
__global__ __launch_bounds__(256) void k_stats(
    const float* __restrict__ logits, const int2* __restrict__ csr,
    const int* __restrict__ start, const int* __restrict__ counts,
    float* __restrict__ m2, float* __restrict__ invden, int N8)
{
    int i = blockIdx.x * 256 + threadIdx.x;
    if (i >= N8) return;
    int n = i >> 3, hh = i & 7;
    int deg = counts[n], s0 = start[n];
    float m = -INFINITY;
    for (int j = 0; j < deg; ++j) {
        int eid = csr[s0 + j].x;
        m = fmaxf(m, logits[(size_t)eid * 8 + hh]);
    }
    float den = 0.f;
    for (int j = 0; j < deg; ++j) {
        int eid = csr[s0 + j].x;
        den += exp2f(logits[(size_t)eid * 8 + hh] - m);
    }
    m2[i] = m;
    invden[i] = 1.f / (den + 1e-9f);
}

// K6: block(128) per node. No shuffles, no online softmax, 1-FMA loop carry.
__global__ __launch_bounds__(128) void k_agg2(
    const float* __restrict__ h, const float* __restrict__ ea,
    const float* __restrict__ We, const float* __restrict__ logits,
    const int2* __restrict__ csr, const int* __restrict__ start,
    const int* __restrict__ counts, const float* __restrict__ m2,
    const float* __restrict__ invden, float* __restrict__ out, int N)
{
    int n = blockIdx.x;
    if (n >= N) return;
    int c = threadIdx.x;             // c = head*16 + d
    int head = c >> 4, d = c & 15;

    float w[16];                      // W_edge column for this (head,d)
#pragma unroll
    for (int i = 0; i < 16; ++i) w[i] = We[head * 256 + i * 16 + d];

    int deg = counts[n], s0 = start[n];
    float mv  = m2[n * 8 + head];
    float idn = invden[n * 8 + head];

    float acc = 0.f;
    for (int j = 0; j < deg; ++j) {
        int2 ce = csr[s0 + j];
        int eid = ce.x, sn = ce.y;
        float kv = h[(size_t)sn * 128 + c];               // coalesced 512B row
        float lg = logits[(size_t)eid * 8 + head];        // 16-lane broadcast
        const float4* e4 = (const float4*)(ea + (size_t)eid * 16);
        float4 a0 = e4[0], a1 = e4[1], a2 = e4[2], a3 = e4[3];
        float ev = a0.x * w[0]  + a0.y * w[1]  + a0.z * w[2]  + a0.w * w[3]
                 + a1.x * w[4]  + a1.y * w[5]  + a1.z * w[6]  + a1.w * w[7]
                 + a2.x * w[8]  + a2.y * w[9]  + a2.z * w[10] + a2.w * w[11]
                 + a3.x * w[12] + a3.y * w[13] + a3.z * w[14] + a3.w * w[15];
        float p  = exp2f(lg - mv);                        // exp(logit - m)
        float sg = 1.f / (1.f + exp2f(ev * -LOG2E));      // sigmoid(ev)
        acc = fmaf(p * sg, kv, acc);
    }
    out[(size_t)n * 128 + c] = acc * idn;
}

extern "C" void kernel_launch(void* const* d_in, const int* in_sizes, int n_in,
                              void* d_out, int out_size, void* d_ws, size_t ws_size,
                              hipStream_t stream)
{
    const float* x  = (const float*)d_in[0];
    const float* ea = (const float*)d_in[1];
    const float* Wn = (const float*)d_in[2];
    const float* We = (const float*)d_in[3];
    const int*  src = (const int*)d_in[4];
    const int*  dst = (const int*)d_in[5];
    float* out = (float*)d_out;

    int N = in_sizes[0] / 128;   // 50000
    int E = in_sizes[4];         // 800000

    char* ws = (char*)d_ws;
    int2*  csr    = (int2*)ws;                               // E int2
    float* h      = (float*)(ws + (size_t)E * 8);            // N*128 f32
    float* logits = h + (size_t)N * 128;                     // E*8 f32
    float* m2     = logits + (size_t)E * 8;                  // N*8 f32
    float* invden = m2 + (size_t)N * 8;                      // N*8 f32
    int*   counts = (int*)(invden + (size_t)N * 8);          // N
    int*   gcur   = counts + N;                              // 1
    int*   start  = gcur + 1;                                // N
    int*   cursor = start + N;                               // N

    hipMemsetAsync(counts, 0, (size_t)(N + 1) * sizeof(int), stream);

    k_hproj  <<<(N + 63) / 64,        256, 0, stream>>>(x, Wn, h, N);
    k_edge   <<<(E * 8 + 255) / 256,  256, 0, stream>>>(h, ea, We, src, dst,
                                                        logits, counts, E);
    k_alloc  <<<(N + 255) / 256,      256, 0, stream>>>(counts, start, cursor, gcur, N);
    k_scatter<<<(E + 255) / 256,      256, 0, stream>>>(src, dst, cursor, csr, E);
    k_stats  <<<(N * 8 + 255) / 256,  256, 0, stream>>>(logits, csr, start, counts,
                                                        m2, invden, N * 8);
    k_agg2   <<<N,                    128, 0, stream>>>(h, ea, We, logits, csr, start,
                                                        counts, m2, invden, out, N);
}

// Round 3
// 368.690 us; speedup vs baseline: 1.1208x; 1.1208x over previous
//
#include <hip/hip_runtime.h>
#include <math.h>

// ---------------------------------------------------------------------------
// EG-GAT layer v3 — no-max softmax, fused edge+scatter, pipelined aggregate:
//   K1 hproj: h[N,128] = x @ W_node
//   K2 hist:  counts[dst]++
//   K3 alloc: CSR segment starts (wave-aggregated cursor, no scan)
//   K4 edge:  per (e,h): logit -> pa=exp(lg); denom atomicAdd; CSR slot via
//             leader-lane atomic + shfl; write csr byte-offsets + pa (CSR order)
//   K5 agg:   block per node; 2-deep SW-pipelined loop:
//             acc += pa * sigmoid(ea.Wcol) * h[src,c];  out = acc/(denom+eps)
// ---------------------------------------------------------------------------

#define LOG2E 1.44269504088896340736f

__global__ __launch_bounds__(256) void k_hproj(
    const float* __restrict__ x, const float* __restrict__ Wn,
    float* __restrict__ h, int N)
{
    int t  = threadIdx.x;
    int cg = t & 31, rg = t >> 5;
    int c0 = cg * 4;
    int hh = c0 >> 4, d0 = c0 & 15;
    int r0 = blockIdx.x * 64 + rg * 8;
    const float* wbase = Wn + hh * 2048 + d0;

    float acc[8][4];
#pragma unroll
    for (int j = 0; j < 8; ++j)
#pragma unroll
        for (int q = 0; q < 4; ++q) acc[j][q] = 0.f;

    int rr[8];
#pragma unroll
    for (int j = 0; j < 8; ++j) { int n = r0 + j; rr[j] = (n < N) ? n : (N - 1); }

    for (int k0 = 0; k0 < 128; k0 += 4) {
        float4 b0 = *(const float4*)(wbase + (k0 + 0) * 16);
        float4 b1 = *(const float4*)(wbase + (k0 + 1) * 16);
        float4 b2 = *(const float4*)(wbase + (k0 + 2) * 16);
        float4 b3 = *(const float4*)(wbase + (k0 + 3) * 16);
#pragma unroll
        for (int j = 0; j < 8; ++j) {
            float4 a = *(const float4*)(x + (size_t)rr[j] * 128 + k0);
            acc[j][0] += a.x * b0.x + a.y * b1.x + a.z * b2.x + a.w * b3.x;
            acc[j][1] += a.x * b0.y + a.y * b1.y + a.z * b2.y + a.w * b3.y;
            acc[j][2] += a.x * b0.z + a.y * b1.z + a.z * b2.z + a.w * b3.z;
            acc[j][3] += a.x * b0.w + a.y * b1.w + a.z * b2.w + a.w * b3.w;
        }
    }
#pragma unroll
    for (int j = 0; j < 8; ++j) {
        int n = r0 + j;
        if (n < N) {
            float4 v = make_float4(acc[j][0], acc[j][1], acc[j][2], acc[j][3]);
            *(float4*)(h + (size_t)n * 128 + c0) = v;
        }
    }
}

__global__ __launch_bounds__(256) void k_hist(
    const int* __restrict__ dst, int* __restrict__ counts, int E)
{
    int e = blockIdx.x * 256 + threadIdx.x;
    if (e < E) atomicAdd(counts + dst[e], 1);
}

__global__ __launch_bounds__(256) void k_alloc(
    const int* __restrict__ counts, int* __restrict__ start,
    int* __restrict__ cursor, int* __restrict__ gcur, int N)
{
    int i = blockIdx.x * 256 + threadIdx.x;
    int lane = threadIdx.x & 63;
    int v = (i < N) ? counts[i] : 0;
    int incl = v;
#pragma unroll
    for (int o = 1; o < 64; o <<= 1) {
        int u = __shfl_up(incl, o);
        if (lane >= o) incl += u;
    }
    int total = __shfl(incl, 63);
    int base = 0;
    if (lane == 63) base = atomicAdd(gcur, total);
    base = __shfl(base, 63);
    int st = base + incl - v;
    if (i < N) { start[i] = st; cursor[i] = st; }
}

// K4: thread per (edge, head). Computes pa = exp(leaky((q.k + ea.cs)/4)),
// accumulates denom, allocates CSR slot (leader lane) and writes pa in CSR
// order plus byte-offset csr entry.
__global__ __launch_bounds__(256) void k_edge(
    const float* __restrict__ h, const float* __restrict__ ea,
    const float* __restrict__ We, const int* __restrict__ src,
    const int* __restrict__ dst, int* __restrict__ cursor,
    int2* __restrict__ csr, float* __restrict__ palpha,
    float* __restrict__ denom, int E)
{
    __shared__ float cs[128];                 // cs[h*16+i] = sum_d We[h][i][d]
    int t = threadIdx.x;
    if (t < 128) {
        const float4* wr = (const float4*)(We + t * 16);
        float4 w0 = wr[0], w1 = wr[1], w2 = wr[2], w3 = wr[3];
        cs[t] = (w0.x + w0.y + w0.z + w0.w) + (w1.x + w1.y + w1.z + w1.w)
              + (w2.x + w2.y + w2.z + w2.w) + (w3.x + w3.y + w3.z + w3.w);
    }
    __syncthreads();

    int gid = blockIdx.x * 256 + t;
    int e = gid >> 3;
    if (e >= E) return;
    int hh = gid & 7;
    int dn = dst[e], sn = src[e];

    const float4* qp = (const float4*)(h + (size_t)dn * 128 + hh * 16);
    const float4* kp = (const float4*)(h + (size_t)sn * 128 + hh * 16);
    float4 q0 = qp[0], q1 = qp[1], q2 = qp[2], q3 = qp[3];
    float4 k0 = kp[0], k1 = kp[1], k2 = kp[2], k3 = kp[3];
    float qk = q0.x*k0.x + q0.y*k0.y + q0.z*k0.z + q0.w*k0.w
             + q1.x*k1.x + q1.y*k1.y + q1.z*k1.z + q1.w*k1.w
             + q2.x*k2.x + q2.y*k2.y + q2.z*k2.z + q2.w*k2.w
             + q3.x*k3.x + q3.y*k3.y + q3.z*k3.z + q3.w*k3.w;

    const float4* ap = (const float4*)(ea + (size_t)e * 16);
    float4 a0 = ap[0], a1 = ap[1], a2 = ap[2], a3 = ap[3];
    const float4* cp = (const float4*)(cs + hh * 16);
    float4 c0 = cp[0], c1 = cp[1], c2 = cp[2], c3 = cp[3];
    float es = a0.x*c0.x + a0.y*c0.y + a0.z*c0.z + a0.w*c0.w
             + a1.x*c1.x + a1.y*c1.y + a1.z*c1.z + a1.w*c1.w
             + a2.x*c2.x + a2.y*c2.y + a2.z*c2.z + a2.w*c2.w
             + a3.x*c3.x + a3.y*c3.y + a3.z*c3.z + a3.w*c3.w;

    float lg = (qk + es) * 0.25f;
    lg = (lg > 0.f) ? lg : 0.2f * lg;         // leaky_relu
    float pa = exp2f(lg * LOG2E);             // exp(logit), no max shift

    atomicAdd(denom + (size_t)dn * 8 + hh, pa);

    int lane = t & 63;
    int pos = 0;
    if ((lane & 7) == 0) pos = atomicAdd(cursor + dn, 1);
    pos = __shfl(pos, lane & 56);             // broadcast within 8-lane group

    palpha[(size_t)pos * 8 + hh] = pa;        // CSR-ordered, 32B/edge
    if ((lane & 7) == 0)
        csr[pos] = make_int2(e << 6, sn << 9);  // byte offsets into ea / h
}

// K5: block(128) per node; 2-deep software-pipelined gather loop.
__global__ __launch_bounds__(128) void k_agg3(
    const float* __restrict__ h, const float* __restrict__ ea,
    const float* __restrict__ We, const float* __restrict__ palpha,
    const int2* __restrict__ csr, const int* __restrict__ start,
    const int* __restrict__ counts, const float* __restrict__ denom,
    float* __restrict__ out, int N)
{
    int n = blockIdx.x;
    if (n >= N) return;
    int c = threadIdx.x;              // c = head*16 + d
    int head = c >> 4, d = c & 15;

    float w[16];
#pragma unroll
    for (int i = 0; i < 16; ++i) w[i] = We[head * 256 + i * 16 + d];

    int deg = counts[n], s0 = start[n];
    float idn = __builtin_amdgcn_rcpf(denom[(size_t)n * 8 + head] + 1e-9f);

    float acc = 0.f;
    if (deg > 0) {
        int dm1 = deg - 1;
        const char* hb = (const char*)h;
        const char* eb = (const char*)ea;
        unsigned c4 = (unsigned)c << 2;

        int2  ceA = csr[s0];
        float paA = palpha[(size_t)s0 * 8 + head];
        float kvA = *(const float*)(hb + (unsigned)ceA.y + c4);
        const float4* pA = (const float4*)(eb + (unsigned)ceA.x);
        float4 a0 = pA[0], a1 = pA[1], a2 = pA[2], a3 = pA[3];

        int j1 = (1 < dm1) ? 1 : dm1;
        int2  ceB = csr[s0 + j1];
        float paB = palpha[(size_t)(s0 + j1) * 8 + head];

        for (int j = 0; j < deg; ++j) {
            // issue loads for edge j+1 (clamped; redundant at tail, harmless)
            float kvB = *(const float*)(hb + (unsigned)ceB.y + c4);
            const float4* pB = (const float4*)(eb + (unsigned)ceB.x);
            float4 b0 = pB[0], b1 = pB[1], b2 = pB[2], b3 = pB[3];
            // prefetch indices for edge j+2
            int jc = j + 2; jc = (jc < dm1) ? jc : dm1;
            int2  ceC = csr[s0 + jc];
            float paC = palpha[(size_t)(s0 + jc) * 8 + head];
            // compute edge j
            float ev = a0.x * w[0]  + a0.y * w[1]  + a0.z * w[2]  + a0.w * w[3]
                     + a1.x * w[4]  + a1.y * w[5]  + a1.z * w[6]  + a1.w * w[7]
                     + a2.x * w[8]  + a2.y * w[9]  + a2.z * w[10] + a2.w * w[11]
                     + a3.x * w[12] + a3.y * w[13] + a3.z * w[14] + a3.w * w[15];
            float sg = __builtin_amdgcn_rcpf(1.f + exp2f(ev * -LOG2E));
            acc = fmaf(paA * sg, kvA, acc);
            // shift pipeline
            kvA = kvB; a0 = b0; a1 = b1; a2 = b2; a3 = b3; paA = paB;
            ceB = ceC; paB = paC;
        }
    }
    out[(size_t)n * 128 + c] = acc * idn;
}

extern "C" void kernel_launch(void* const* d_in, const int* in_sizes, int n_in,
                              void* d_out, int out_size, void* d_ws, size_t ws_size,
                              hipStream_t stream)
{
    const float* x  = (const float*)d_in[0];
    const float* ea = (const float*)d_in[1];
    const float* Wn = (const float*)d_in[2];
    const float* We = (const float*)d_in[3];
    const int*  src = (const int*)d_in[4];
    const int*  dst = (const int*)d_in[5];
    float* out = (float*)d_out;

    int N = in_sizes[0] / 128;   // 50000
    int E = in_sizes[4];         // 800000

    char* ws = (char*)d_ws;
    int2*  csr    = (int2*)ws;                               // E int2
    float* h      = (float*)(ws + (size_t)E * 8);            // N*128
    float* palpha = h + (size_t)N * 128;                     // E*8
    int*   counts = (int*)(palpha + (size_t)E * 8);          // N
    int*   gcur   = counts + N;                              // 1
    float* denom  = (float*)(gcur + 1);                      // N*8
    int*   start  = (int*)(denom + (size_t)N * 8);           // N
    int*   cursor = start + N;                               // N

    // zero counts + gcur + denom in one contiguous shot
    hipMemsetAsync(counts, 0, (size_t)(N + 1) * 4 + (size_t)N * 32, stream);

    k_hproj<<<(N + 63) / 64,       256, 0, stream>>>(x, Wn, h, N);
    k_hist <<<(E + 255) / 256,     256, 0, stream>>>(dst, counts, E);
    k_alloc<<<(N + 255) / 256,     256, 0, stream>>>(counts, start, cursor, gcur, N);
    k_edge <<<(E * 8 + 255) / 256, 256, 0, stream>>>(h, ea, We, src, dst, cursor,
                                                     csr, palpha, denom, E);
    k_agg3 <<<N,                   128, 0, stream>>>(h, ea, We, palpha, csr, start,
                                                     counts, denom, out, N);
}

// Round 5
// 323.981 us; speedup vs baseline: 1.2755x; 1.1380x over previous
//
#include <hip/hip_runtime.h>
#include <math.h>

// ---------------------------------------------------------------------------
// EG-GAT layer v5 — v4 (f16 storage + dot2, CSR-ordered logits) with the f16
// palpha overflow fixed: palpha stays f32 (exp(logit) can exceed 65504).
//   K1 hproj:   h16[N,128] (f16) = x @ W_node
//   K2 hist:    counts[dst]++  (fused: ea -> ea16 f16 conversion)
//   K3 alloc:   CSR segment starts (wave-aggregated cursor)
//   K4 scatter: csr[pos] = (eid<<5, src<<8) byte-offsets, sdst[pos] = dst<<8
//   K5 edge2:   CSR-order logits: q row L1-hot, k/ea f16 gathers, fdot2;
//               palpha[slot] = exp(logit) f32 (sequential write, no atomics)
//   K6 agg4:    block/node; fdot2 gate; den += pa in-loop; out = acc/den
// ---------------------------------------------------------------------------

#define LOG2E 1.44269504088896340736f

typedef _Float16 h2 __attribute__((ext_vector_type(2)));
typedef _Float16 h4 __attribute__((ext_vector_type(4)));

__device__ __forceinline__ float fdot2(h2 a, h2 b, float c) {
    return __builtin_amdgcn_fdot2(a, b, c, false);
}
__device__ __forceinline__ h2 bch(unsigned u) {
    return __builtin_bit_cast(h2, u);
}

// K1: register-blocked GEMM, f16 output.
__global__ __launch_bounds__(256) void k_hproj(
    const float* __restrict__ x, const float* __restrict__ Wn,
    _Float16* __restrict__ h16, int N)
{
    int t  = threadIdx.x;
    int cg = t & 31, rg = t >> 5;
    int c0 = cg * 4;
    int hh = c0 >> 4, d0 = c0 & 15;
    int r0 = blockIdx.x * 64 + rg * 8;
    const float* wbase = Wn + hh * 2048 + d0;

    float acc[8][4];
#pragma unroll
    for (int j = 0; j < 8; ++j)
#pragma unroll
        for (int q = 0; q < 4; ++q) acc[j][q] = 0.f;

    int rr[8];
#pragma unroll
    for (int j = 0; j < 8; ++j) { int n = r0 + j; rr[j] = (n < N) ? n : (N - 1); }

    for (int k0 = 0; k0 < 128; k0 += 4) {
        float4 b0 = *(const float4*)(wbase + (k0 + 0) * 16);
        float4 b1 = *(const float4*)(wbase + (k0 + 1) * 16);
        float4 b2 = *(const float4*)(wbase + (k0 + 2) * 16);
        float4 b3 = *(const float4*)(wbase + (k0 + 3) * 16);
#pragma unroll
        for (int j = 0; j < 8; ++j) {
            float4 a = *(const float4*)(x + (size_t)rr[j] * 128 + k0);
            acc[j][0] += a.x * b0.x + a.y * b1.x + a.z * b2.x + a.w * b3.x;
            acc[j][1] += a.x * b0.y + a.y * b1.y + a.z * b2.y + a.w * b3.y;
            acc[j][2] += a.x * b0.z + a.y * b1.z + a.z * b2.z + a.w * b3.z;
            acc[j][3] += a.x * b0.w + a.y * b1.w + a.z * b2.w + a.w * b3.w;
        }
    }
#pragma unroll
    for (int j = 0; j < 8; ++j) {
        int n = r0 + j;
        if (n < N) {
            h4 v = { (_Float16)acc[j][0], (_Float16)acc[j][1],
                     (_Float16)acc[j][2], (_Float16)acc[j][3] };
            *(h4*)(h16 + (size_t)n * 128 + c0) = v;
        }
    }
}

// K2: degree histogram + ea f32->f16 conversion (streaming).
__global__ __launch_bounds__(256) void k_hist(
    const int* __restrict__ dst, const float* __restrict__ ea,
    _Float16* __restrict__ ea16, int* __restrict__ counts, int E)
{
    int e = blockIdx.x * 256 + threadIdx.x;
    if (e >= E) return;
    atomicAdd(counts + dst[e], 1);
    const float4* ap = (const float4*)(ea + (size_t)e * 16);
    float4 a0 = ap[0], a1 = ap[1], a2 = ap[2], a3 = ap[3];
    h4* op = (h4*)(ea16 + (size_t)e * 16);
    op[0] = h4{(_Float16)a0.x, (_Float16)a0.y, (_Float16)a0.z, (_Float16)a0.w};
    op[1] = h4{(_Float16)a1.x, (_Float16)a1.y, (_Float16)a1.z, (_Float16)a1.w};
    op[2] = h4{(_Float16)a2.x, (_Float16)a2.y, (_Float16)a2.z, (_Float16)a2.w};
    op[3] = h4{(_Float16)a3.x, (_Float16)a3.y, (_Float16)a3.z, (_Float16)a3.w};
}

__global__ __launch_bounds__(256) void k_alloc(
    const int* __restrict__ counts, int* __restrict__ start,
    int* __restrict__ cursor, int* __restrict__ gcur, int N)
{
    int i = blockIdx.x * 256 + threadIdx.x;
    int lane = threadIdx.x & 63;
    int v = (i < N) ? counts[i] : 0;
    int incl = v;
#pragma unroll
    for (int o = 1; o < 64; o <<= 1) {
        int u = __shfl_up(incl, o);
        if (lane >= o) incl += u;
    }
    int total = __shfl(incl, 63);
    int base = 0;
    if (lane == 63) base = atomicAdd(gcur, total);
    base = __shfl(base, 63);
    int st = base + incl - v;
    if (i < N) { start[i] = st; cursor[i] = st; }
}

// K4: bucket edges by dst; store byte offsets (ea16: e<<5, h16: n<<8).
__global__ __launch_bounds__(256) void k_scatter(
    const int* __restrict__ src, const int* __restrict__ dst,
    int* __restrict__ cursor, int2* __restrict__ csr,
    int* __restrict__ sdst, int E)
{
    int e = blockIdx.x * 256 + threadIdx.x;
    if (e < E) {
        int dn = dst[e];
        int pos = atomicAdd(cursor + dn, 1);
        csr[pos] = make_int2(e << 5, src[e] << 8);
        sdst[pos] = dn << 8;
    }
}

// K5: thread per (CSR slot, head). q row L1-hot (dst-sorted order); k and ea
// are f16 gathers; all dots via v_dot2_f32_f16. Sequential f32 palpha write.
__global__ __launch_bounds__(256) void k_edge2(
    const _Float16* __restrict__ h16, const _Float16* __restrict__ ea16,
    const float* __restrict__ We, const int2* __restrict__ csr,
    const int* __restrict__ sdst, float* __restrict__ palpha, int E)
{
    __shared__ unsigned cs16[64];        // packed h2: colsum of We per (h, i-pair)
    int t = threadIdx.x;
    if (t < 64) {
        int hh = t >> 3, i = t & 7;
        const float* r0 = We + (hh * 16 + 2 * i) * 16;
        float s0 = 0.f, s1 = 0.f;
#pragma unroll
        for (int d = 0; d < 16; ++d) { s0 += r0[d]; s1 += r0[16 + d]; }
        h2 p = { (_Float16)s0, (_Float16)s1 };
        cs16[t] = __builtin_bit_cast(unsigned, p);
    }
    __syncthreads();

    int gid = blockIdx.x * 256 + t;
    int slot = gid >> 3;
    if (slot >= E) return;
    int hh = gid & 7;

    int2 ce = csr[slot];
    int dnb = sdst[slot];
    const char* hb = (const char*)h16;
    const char* eb = (const char*)ea16;

    uint4 qa = *(const uint4*)(hb + dnb + (hh << 5));
    uint4 qb = *(const uint4*)(hb + dnb + (hh << 5) + 16);
    uint4 ka = *(const uint4*)(hb + (unsigned)ce.y + (hh << 5));
    uint4 kb = *(const uint4*)(hb + (unsigned)ce.y + (hh << 5) + 16);
    uint4 ga = *(const uint4*)(eb + (unsigned)ce.x);
    uint4 gb = *(const uint4*)(eb + (unsigned)ce.x + 16);
    uint4 ca = *(const uint4*)&cs16[hh << 3];
    uint4 cb = *(const uint4*)&cs16[(hh << 3) + 4];

    float qk = 0.f;
    qk = fdot2(bch(qa.x), bch(ka.x), qk);
    qk = fdot2(bch(qa.y), bch(ka.y), qk);
    qk = fdot2(bch(qa.z), bch(ka.z), qk);
    qk = fdot2(bch(qa.w), bch(ka.w), qk);
    qk = fdot2(bch(qb.x), bch(kb.x), qk);
    qk = fdot2(bch(qb.y), bch(kb.y), qk);
    qk = fdot2(bch(qb.z), bch(kb.z), qk);
    qk = fdot2(bch(qb.w), bch(kb.w), qk);
    float es = 0.f;
    es = fdot2(bch(ga.x), bch(ca.x), es);
    es = fdot2(bch(ga.y), bch(ca.y), es);
    es = fdot2(bch(ga.z), bch(ca.z), es);
    es = fdot2(bch(ga.w), bch(ca.w), es);
    es = fdot2(bch(gb.x), bch(cb.x), es);
    es = fdot2(bch(gb.y), bch(cb.y), es);
    es = fdot2(bch(gb.z), bch(cb.z), es);
    es = fdot2(bch(gb.w), bch(cb.w), es);

    float lg = (qk + es) * 0.25f;
    lg = (lg > 0.f) ? lg : 0.2f * lg;        // leaky_relu
    float pa = exp2f(lg * LOG2E);            // exp(logit), no max shift (f32 safe)
    palpha[((size_t)slot << 3) + hh] = pa;
}

// K6: block(128) per node; fdot2 gate; denominator accumulated in-loop.
__global__ __launch_bounds__(128) void k_agg4(
    const _Float16* __restrict__ h16, const _Float16* __restrict__ ea16,
    const float* __restrict__ We, const float* __restrict__ palpha,
    const int2* __restrict__ csr, const int* __restrict__ start,
    const int* __restrict__ counts, float* __restrict__ out, int N)
{
    int n = blockIdx.x;
    if (n >= N) return;
    int c = threadIdx.x;              // c = head*16 + d
    int head = c >> 4, d = c & 15;

    h2 w2[8];                          // W_edge column, packed pairs along i
#pragma unroll
    for (int i = 0; i < 8; ++i) {
        float w0 = We[head * 256 + (2 * i) * 16 + d];
        float w1 = We[head * 256 + (2 * i + 1) * 16 + d];
        w2[i] = h2{ (_Float16)w0, (_Float16)w1 };
    }

    int deg = counts[n], s0 = start[n];
    const char* hb = (const char*)h16;
    const char* eb = (const char*)ea16;

    float acc = 0.f, den = 0.f;
    if (deg > 0) {
        int dm1 = deg - 1;
        unsigned c2 = (unsigned)c << 1;

        int2  ceA = csr[s0];
        float paA = palpha[((size_t)s0 << 3) + head];
        _Float16 kvA = *(const _Float16*)(hb + (unsigned)ceA.y + c2);
        uint4 ea0 = *(const uint4*)(eb + (unsigned)ceA.x);
        uint4 ea1 = *(const uint4*)(eb + (unsigned)ceA.x + 16);

        int j1 = (1 < dm1) ? 1 : dm1;
        int2  ceB = csr[s0 + j1];
        float paB = palpha[((size_t)(s0 + j1) << 3) + head];

        for (int j = 0; j < deg; ++j) {
            // loads for edge j+1 (clamped at tail)
            _Float16 kvB = *(const _Float16*)(hb + (unsigned)ceB.y + c2);
            uint4 eb0 = *(const uint4*)(eb + (unsigned)ceB.x);
            uint4 eb1 = *(const uint4*)(eb + (unsigned)ceB.x + 16);
            // indices for edge j+2
            int jc = j + 2; jc = (jc < dm1) ? jc : dm1;
            int2  ceC = csr[s0 + jc];
            float paC = palpha[((size_t)(s0 + jc) << 3) + head];
            // compute edge j
            float ev = 0.f;
            ev = fdot2(bch(ea0.x), w2[0], ev);
            ev = fdot2(bch(ea0.y), w2[1], ev);
            ev = fdot2(bch(ea0.z), w2[2], ev);
            ev = fdot2(bch(ea0.w), w2[3], ev);
            ev = fdot2(bch(ea1.x), w2[4], ev);
            ev = fdot2(bch(ea1.y), w2[5], ev);
            ev = fdot2(bch(ea1.z), w2[6], ev);
            ev = fdot2(bch(ea1.w), w2[7], ev);
            float sg = __builtin_amdgcn_rcpf(1.f + exp2f(ev * -LOG2E));
            den += paA;
            acc = fmaf(paA * sg, (float)kvA, acc);
            // rotate pipeline
            kvA = kvB; ea0 = eb0; ea1 = eb1; paA = paB;
            ceB = ceC; paB = paC;
        }
    }
    out[(size_t)n * 128 + c] = acc * __builtin_amdgcn_rcpf(den + 1e-9f);
}

extern "C" void kernel_launch(void* const* d_in, const int* in_sizes, int n_in,
                              void* d_out, int out_size, void* d_ws, size_t ws_size,
                              hipStream_t stream)
{
    const float* x  = (const float*)d_in[0];
    const float* ea = (const float*)d_in[1];
    const float* Wn = (const float*)d_in[2];
    const float* We = (const float*)d_in[3];
    const int*  src = (const int*)d_in[4];
    const int*  dst = (const int*)d_in[5];
    float* out = (float*)d_out;

    int N = in_sizes[0] / 128;   // 50000
    int E = in_sizes[4];         // 800000

    char* ws = (char*)d_ws;
    int2*      csr    = (int2*)ws;                              // E*8   = 6.4MB
    int*       sdst   = (int*)(ws + (size_t)E * 8);             // E*4   = 3.2MB
    _Float16*  h16    = (_Float16*)(ws + (size_t)E * 12);       // N*256 = 12.8MB
    _Float16*  ea16   = h16 + (size_t)N * 128;                  // E*32  = 25.6MB
    float*     palpha = (float*)(ea16 + (size_t)E * 16);        // E*32  = 25.6MB
    int*       counts = (int*)(palpha + (size_t)E * 8);         // N
    int*       gcur   = counts + N;                             // 1
    int*       start  = gcur + 1;                               // N
    int*       cursor = start + N;                              // N

    hipMemsetAsync(counts, 0, (size_t)(N + 1) * sizeof(int), stream);

    k_hproj  <<<(N + 63) / 64,       256, 0, stream>>>(x, Wn, h16, N);
    k_hist   <<<(E + 255) / 256,     256, 0, stream>>>(dst, ea, ea16, counts, E);
    k_alloc  <<<(N + 255) / 256,     256, 0, stream>>>(counts, start, cursor, gcur, N);
    k_scatter<<<(E + 255) / 256,     256, 0, stream>>>(src, dst, cursor, csr, sdst, E);
    k_edge2  <<<(E * 8 + 255) / 256, 256, 0, stream>>>(h16, ea16, We, csr, sdst,
                                                       palpha, E);
    k_agg4   <<<N,                   128, 0, stream>>>(h16, ea16, We, palpha, csr,
                                                       start, counts, out, N);
}

// Round 6
// 302.186 us; speedup vs baseline: 1.3675x; 1.0721x over previous
//
#include <hip/hip_runtime.h>
#include <math.h>

// ---------------------------------------------------------------------------
// EG-GAT layer v6 — single fused edge pass:
//   K1 hproj:   h16[N,128] (f16) = x @ W_node
//   K2 hist:    counts[dst]++  (fused: ea -> ea16 f16 conversion)
//   K3 alloc:   CSR segment starts (wave-aggregated cursor)
//   K4 scatter: csr[pos] = (eid<<5, src<<8) byte-offsets
//   K5 fused:   block(128)/node. Per edge: shared k-gather feeds BOTH the
//               logit (1 FMA + 4-step shfl_xor tree within 16-lane head
//               group; ea colsum term folded in as 1 FMA) AND the gated
//               message. den += pa in-loop. No palpha buffer, no 2nd gather.
// ---------------------------------------------------------------------------

#define LOG2E 1.44269504088896340736f

typedef _Float16 h2 __attribute__((ext_vector_type(2)));
typedef _Float16 h4 __attribute__((ext_vector_type(4)));

__device__ __forceinline__ float fdot2(h2 a, h2 b, float c) {
    return __builtin_amdgcn_fdot2(a, b, c, false);
}
__device__ __forceinline__ h2 bch(unsigned u) {
    return __builtin_bit_cast(h2, u);
}

// K1: register-blocked GEMM, f16 output.
__global__ __launch_bounds__(256) void k_hproj(
    const float* __restrict__ x, const float* __restrict__ Wn,
    _Float16* __restrict__ h16, int N)
{
    int t  = threadIdx.x;
    int cg = t & 31, rg = t >> 5;
    int c0 = cg * 4;
    int hh = c0 >> 4, d0 = c0 & 15;
    int r0 = blockIdx.x * 64 + rg * 8;
    const float* wbase = Wn + hh * 2048 + d0;

    float acc[8][4];
#pragma unroll
    for (int j = 0; j < 8; ++j)
#pragma unroll
        for (int q = 0; q < 4; ++q) acc[j][q] = 0.f;

    int rr[8];
#pragma unroll
    for (int j = 0; j < 8; ++j) { int n = r0 + j; rr[j] = (n < N) ? n : (N - 1); }

    for (int k0 = 0; k0 < 128; k0 += 4) {
        float4 b0 = *(const float4*)(wbase + (k0 + 0) * 16);
        float4 b1 = *(const float4*)(wbase + (k0 + 1) * 16);
        float4 b2 = *(const float4*)(wbase + (k0 + 2) * 16);
        float4 b3 = *(const float4*)(wbase + (k0 + 3) * 16);
#pragma unroll
        for (int j = 0; j < 8; ++j) {
            float4 a = *(const float4*)(x + (size_t)rr[j] * 128 + k0);
            acc[j][0] += a.x * b0.x + a.y * b1.x + a.z * b2.x + a.w * b3.x;
            acc[j][1] += a.x * b0.y + a.y * b1.y + a.z * b2.y + a.w * b3.y;
            acc[j][2] += a.x * b0.z + a.y * b1.z + a.z * b2.z + a.w * b3.z;
            acc[j][3] += a.x * b0.w + a.y * b1.w + a.z * b2.w + a.w * b3.w;
        }
    }
#pragma unroll
    for (int j = 0; j < 8; ++j) {
        int n = r0 + j;
        if (n < N) {
            h4 v = { (_Float16)acc[j][0], (_Float16)acc[j][1],
                     (_Float16)acc[j][2], (_Float16)acc[j][3] };
            *(h4*)(h16 + (size_t)n * 128 + c0) = v;
        }
    }
}

// K2: degree histogram + ea f32->f16 conversion (streaming).
__global__ __launch_bounds__(256) void k_hist(
    const int* __restrict__ dst, const float* __restrict__ ea,
    _Float16* __restrict__ ea16, int* __restrict__ counts, int E)
{
    int e = blockIdx.x * 256 + threadIdx.x;
    if (e >= E) return;
    atomicAdd(counts + dst[e], 1);
    const float4* ap = (const float4*)(ea + (size_t)e * 16);
    float4 a0 = ap[0], a1 = ap[1], a2 = ap[2], a3 = ap[3];
    h4* op = (h4*)(ea16 + (size_t)e * 16);
    op[0] = h4{(_Float16)a0.x, (_Float16)a0.y, (_Float16)a0.z, (_Float16)a0.w};
    op[1] = h4{(_Float16)a1.x, (_Float16)a1.y, (_Float16)a1.z, (_Float16)a1.w};
    op[2] = h4{(_Float16)a2.x, (_Float16)a2.y, (_Float16)a2.z, (_Float16)a2.w};
    op[3] = h4{(_Float16)a3.x, (_Float16)a3.y, (_Float16)a3.z, (_Float16)a3.w};
}

__global__ __launch_bounds__(256) void k_alloc(
    const int* __restrict__ counts, int* __restrict__ start,
    int* __restrict__ cursor, int* __restrict__ gcur, int N)
{
    int i = blockIdx.x * 256 + threadIdx.x;
    int lane = threadIdx.x & 63;
    int v = (i < N) ? counts[i] : 0;
    int incl = v;
#pragma unroll
    for (int o = 1; o < 64; o <<= 1) {
        int u = __shfl_up(incl, o);
        if (lane >= o) incl += u;
    }
    int total = __shfl(incl, 63);
    int base = 0;
    if (lane == 63) base = atomicAdd(gcur, total);
    base = __shfl(base, 63);
    int st = base + incl - v;
    if (i < N) { start[i] = st; cursor[i] = st; }
}

// K4: bucket edges by dst; store byte offsets (ea16: e<<5, h16: n<<8).
__global__ __launch_bounds__(256) void k_scatter(
    const int* __restrict__ src, const int* __restrict__ dst,
    int* __restrict__ cursor, int2* __restrict__ csr, int E)
{
    int e = blockIdx.x * 256 + threadIdx.x;
    if (e < E) {
        int dn = dst[e];
        int pos = atomicAdd(cursor + dn, 1);
        csr[pos] = make_int2(e << 5, src[e] << 8);
    }
}

// K5: block(128) per node. Shared gather feeds logit + message.
__global__ __launch_bounds__(128) void k_fused(
    const _Float16* __restrict__ h16, const _Float16* __restrict__ ea16,
    const float* __restrict__ We, const int2* __restrict__ csr,
    const int* __restrict__ start, const int* __restrict__ counts,
    float* __restrict__ out, int N)
{
    int n = blockIdx.x;
    if (n >= N) return;
    int c = threadIdx.x;              // c = head*16 + d
    int head = c >> 4, d = c & 15;

    // gate column W_edge[head][:,d], packed in f16 pairs along i
    h2 w2[8];
#pragma unroll
    for (int i = 0; i < 8; ++i) {
        float w0 = We[head * 256 + (2 * i) * 16 + d];
        float w1 = We[head * 256 + (2 * i + 1) * 16 + d];
        w2[i] = h2{ (_Float16)w0, (_Float16)w1 };
    }
    // colsum term: csv = sum_dd We[head][d][dd]  (lane contributes ea[d]*csv)
    const float4* wr = (const float4*)(We + head * 256 + d * 16);
    float4 s0v = wr[0], s1v = wr[1], s2v = wr[2], s3v = wr[3];
    float csv = (s0v.x + s0v.y + s0v.z + s0v.w) + (s1v.x + s1v.y + s1v.z + s1v.w)
              + (s2v.x + s2v.y + s2v.z + s2v.w) + (s3v.x + s3v.y + s3v.z + s3v.w);

    float q_c = (float)h16[(size_t)n * 128 + c];
    int deg = counts[n], s0 = start[n];
    const char* hb = (const char*)h16;
    const char* eb = (const char*)ea16;

    float acc = 0.f, den = 0.f;
    if (deg > 0) {
        int dm1 = deg - 1;
        unsigned c2 = (unsigned)c << 1, d2 = (unsigned)d << 1;

        int2 ceA = csr[s0];
        float kvA  = (float)(*(const _Float16*)(hb + (unsigned)ceA.y + c2));
        float eadA = (float)(*(const _Float16*)(eb + (unsigned)ceA.x + d2));
        uint4 e0A = *(const uint4*)(eb + (unsigned)ceA.x);
        uint4 e1A = *(const uint4*)(eb + (unsigned)ceA.x + 16);

        int j1 = (1 < dm1) ? 1 : dm1;
        int2 ceB = csr[s0 + j1];

        for (int j = 0; j < deg; ++j) {
            // loads for edge j+1 (clamped at tail)
            float kvB  = (float)(*(const _Float16*)(hb + (unsigned)ceB.y + c2));
            float eadB = (float)(*(const _Float16*)(eb + (unsigned)ceB.x + d2));
            uint4 e0B = *(const uint4*)(eb + (unsigned)ceB.x);
            uint4 e1B = *(const uint4*)(eb + (unsigned)ceB.x + 16);
            int jc = j + 2; jc = (jc < dm1) ? jc : dm1;
            int2 ceC = csr[s0 + jc];

            // ---- compute edge j ----
            // logit: per-lane partial (q.k element + colsum element), 16-lane tree
            float part = fmaf(q_c, kvA, eadA * csv);
            part += __shfl_xor(part, 1);
            part += __shfl_xor(part, 2);
            part += __shfl_xor(part, 4);
            part += __shfl_xor(part, 8);
            float lg = part * 0.25f;
            lg = (lg > 0.f) ? lg : 0.2f * lg;          // leaky_relu
            float pa = exp2f(lg * LOG2E);              // exp(logit), f32 safe

            // gate: ev = ea . We[:,d]
            float ev = 0.f;
            ev = fdot2(bch(e0A.x), w2[0], ev);
            ev = fdot2(bch(e0A.y), w2[1], ev);
            ev = fdot2(bch(e0A.z), w2[2], ev);
            ev = fdot2(bch(e0A.w), w2[3], ev);
            ev = fdot2(bch(e1A.x), w2[4], ev);
            ev = fdot2(bch(e1A.y), w2[5], ev);
            ev = fdot2(bch(e1A.z), w2[6], ev);
            ev = fdot2(bch(e1A.w), w2[7], ev);
            float sg = __builtin_amdgcn_rcpf(1.f + exp2f(ev * -LOG2E));

            den += pa;
            acc = fmaf(pa * sg, kvA, acc);

            // rotate pipeline
            kvA = kvB; eadA = eadB; e0A = e0B; e1A = e1B; ceB = ceC;
        }
    }
    out[(size_t)n * 128 + c] = acc * __builtin_amdgcn_rcpf(den + 1e-9f);
}

extern "C" void kernel_launch(void* const* d_in, const int* in_sizes, int n_in,
                              void* d_out, int out_size, void* d_ws, size_t ws_size,
                              hipStream_t stream)
{
    const float* x  = (const float*)d_in[0];
    const float* ea = (const float*)d_in[1];
    const float* Wn = (const float*)d_in[2];
    const float* We = (const float*)d_in[3];
    const int*  src = (const int*)d_in[4];
    const int*  dst = (const int*)d_in[5];
    float* out = (float*)d_out;

    int N = in_sizes[0] / 128;   // 50000
    int E = in_sizes[4];         // 800000

    char* ws = (char*)d_ws;
    int2*      csr    = (int2*)ws;                              // E*8   = 6.4MB
    _Float16*  h16    = (_Float16*)(ws + (size_t)E * 8);        // N*256 = 12.8MB
    _Float16*  ea16   = h16 + (size_t)N * 128;                  // E*32  = 25.6MB
    int*       counts = (int*)(ea16 + (size_t)E * 16);          // N
    int*       gcur   = counts + N;                             // 1
    int*       start  = gcur + 1;                               // N
    int*       cursor = start + N;                              // N

    hipMemsetAsync(counts, 0, (size_t)(N + 1) * sizeof(int), stream);

    k_hproj  <<<(N + 63) / 64,   256, 0, stream>>>(x, Wn, h16, N);
    k_hist   <<<(E + 255) / 256, 256, 0, stream>>>(dst, ea, ea16, counts, E);
    k_alloc  <<<(N + 255) / 256, 256, 0, stream>>>(counts, start, cursor, gcur, N);
    k_scatter<<<(E + 255) / 256, 256, 0, stream>>>(src, dst, cursor, csr, E);
    k_fused  <<<N,               128, 0, stream>>>(h16, ea16, We, csr, start,
                                                   counts, out, N);
}